// Round 1
// baseline (1736.319 us; speedup 1.0000x reference)
//
#include <hip/hip_runtime.h>
#include <hip/hip_bf16.h>

// ---------------- conv1: [8,3,448,448] (channel-reversed) -> [8,64,150,150], 5x5 s3 p2, ReLU
__global__ void __launch_bounds__(256) conv1_k(const float* __restrict__ x,
                                               const float* __restrict__ w,
                                               const float* __restrict__ bias,
                                               float* __restrict__ out) {
  int idx = blockIdx.x * 256 + threadIdx.x;
  const int HW = 150 * 150;
  if (idx >= 8 * 64 * HW) return;
  int px = idx % 150;
  int py = (idx / 150) % 150;
  int o  = (idx / HW) % 64;
  int b  = idx / (64 * HW);
  float acc = bias[o];
  int iy0 = py * 3 - 2, ix0 = px * 3 - 2;
  for (int c = 0; c < 3; ++c) {
    // fusion reorder: weight channel c multiplies x channel (2-c)
    const float* xp = x + ((size_t)(b * 3 + (2 - c)) * 448) * 448;
    const float* wp = w + (o * 3 + c) * 25;
    for (int ky = 0; ky < 5; ++ky) {
      int iy = iy0 + ky;
      if (iy < 0 || iy >= 448) continue;
      const float* xrow = xp + iy * 448;
      for (int kx = 0; kx < 5; ++kx) {
        int ix = ix0 + kx;
        if (ix < 0 || ix >= 448) continue;
        acc += xrow[ix] * wp[ky * 5 + kx];
      }
    }
  }
  out[idx] = fmaxf(acc, 0.f);
}

// ---------------- conv2: [8,64,150,150] -> [8,32,50,50], 5x5 s3 p2, ReLU
__global__ void __launch_bounds__(256) conv2_k(const float* __restrict__ h1,
                                               const float* __restrict__ w,
                                               const float* __restrict__ bias,
                                               float* __restrict__ ft) {
  __shared__ float ws_[64 * 25];
  int bo = blockIdx.x;            // b*32 + o
  int b = bo >> 5, o = bo & 31;
  for (int i = threadIdx.x; i < 1600; i += 256)
    ws_[i] = w[o * 1600 + i];
  __syncthreads();
  int p = blockIdx.y * 256 + threadIdx.x;
  if (p >= 2500) return;
  int px = p % 50, py = p / 50;
  int iy0 = py * 3 - 2, ix0 = px * 3 - 2;
  float acc = bias[o];
  for (int c = 0; c < 64; ++c) {
    const float* hp = h1 + ((size_t)(b * 64 + c) * 150) * 150;
    const float* wp = ws_ + c * 25;
    for (int ky = 0; ky < 5; ++ky) {
      int iy = iy0 + ky;
      if (iy < 0 || iy >= 150) continue;
      const float* hrow = hp + iy * 150;
      for (int kx = 0; kx < 5; ++kx) {
        int ix = ix0 + kx;
        if (ix < 0 || ix >= 150) continue;
        acc += hrow[ix] * wp[ky * 5 + kx];
      }
    }
  }
  ft[(size_t)(b * 32 + o) * 2500 + p] = fmaxf(acc, 0.f);
}

// ---------------- feature branch (whole thing in one block, 512 threads)
__global__ void __launch_bounds__(512) feat_k(
    const float* __restrict__ xf, const float* __restrict__ enc_w, const float* __restrict__ enc_b,
    const float* __restrict__ wq, const float* __restrict__ bq,
    const float* __restrict__ wk, const float* __restrict__ bk,
    const float* __restrict__ wv, const float* __restrict__ bv,
    const float* __restrict__ wo, const float* __restrict__ bo,
    const float* __restrict__ dec_w, const float* __restrict__ dec_b,
    float* __restrict__ f2out) {
  __shared__ float f[8][512];
  __shared__ float q[8][512];
  __shared__ float kk[8][512];
  __shared__ float v[8][512];
  __shared__ float ao[8][512];
  __shared__ float att[2][8][8];
  __shared__ float xfs[8][36];
  int t = threadIdx.x;
  for (int i = t; i < 288; i += 512) xfs[i / 36][i % 36] = xf[i];
  __syncthreads();
  // f = relu(xf @ enc_w + enc_b)  [8,512]
  for (int i = t; i < 4096; i += 512) {
    int b = i >> 9, j = i & 511;
    float acc = enc_b[j];
    for (int c = 0; c < 36; ++c) acc += xfs[b][c] * enc_w[c * 512 + j];
    f[b][j] = fmaxf(acc, 0.f);
  }
  __syncthreads();
  // q,k,v
  for (int i = t; i < 4096; i += 512) {
    int b = i >> 9, j = i & 511;
    float aq = bq[j], ak = bk[j], av = bv[j];
    for (int c = 0; c < 512; ++c) {
      float fv = f[b][c];
      aq += fv * wq[c * 512 + j];
      ak += fv * wk[c * 512 + j];
      av += fv * wv[c * 512 + j];
    }
    q[b][j] = aq; kk[b][j] = ak; v[b][j] = av;
  }
  __syncthreads();
  // scores + softmax per (head,row)
  if (t < 16) {
    int h = t >> 3, b = t & 7;
    float sc[8];
    float mx = -1e30f;
    for (int c = 0; c < 8; ++c) {
      float acc = 0.f;
      for (int d = 0; d < 256; ++d) acc += q[b][h * 256 + d] * kk[c][h * 256 + d];
      acc *= (1.0f / 16.0f);  // 1/sqrt(256)
      sc[c] = acc;
      mx = fmaxf(mx, acc);
    }
    float s = 0.f;
    for (int c = 0; c < 8; ++c) { sc[c] = expf(sc[c] - mx); s += sc[c]; }
    for (int c = 0; c < 8; ++c) att[h][b][c] = sc[c] / s;
  }
  __syncthreads();
  // ao[b][j] = sum_c att[h][b][c] * v[c][j]   (h = j>>8)
  for (int i = t; i < 4096; i += 512) {
    int b = i >> 9, j = i & 511;
    int h = j >> 8;
    float acc = 0.f;
    for (int c = 0; c < 8; ++c) acc += att[h][b][c] * v[c][j];
    ao[b][j] = acc;
  }
  __syncthreads();
  // o = ao @ wo + bo  (store into q)
  for (int i = t; i < 4096; i += 512) {
    int b = i >> 9, j = i & 511;
    float acc = bo[j];
    for (int c = 0; c < 512; ++c) acc += ao[b][c] * wo[c * 512 + j];
    q[b][j] = acc;
  }
  __syncthreads();
  // f2 = relu(o @ dec_w + dec_b)  [8,32]
  for (int i = t; i < 256; i += 512) {
    int b = i >> 5, j = i & 31;
    float acc = dec_b[j];
    for (int c = 0; c < 512; ++c) acc += q[b][c] * dec_w[c * 32 + j];
    f2out[i] = fmaxf(acc, 0.f);
  }
}

// ---------------- hypergraph G per sample: feat [32,2500] -> G [32,32]
__global__ void __launch_bounds__(256) hg_G_k(const float* __restrict__ ft,
                                              float* __restrict__ Gout) {
  int b = blockIdx.x;
  const float* feat = ft + (size_t)b * 32 * 2500;
  __shared__ float gram[32][32];
  __shared__ float d[32][32];
  __shared__ float avg[32];
  __shared__ float Hm[32][32];
  __shared__ float Hn[32][32];
  __shared__ float DE[32];
  __shared__ float dvi[32];
  int t = threadIdx.x;
  // gram = feat @ feat.T (upper triangle + mirror)
  for (int e = t; e < 1024; e += 256) {
    int i = e >> 5, j = e & 31;
    if (j < i) continue;
    float acc = 0.f;
    const float* fi = feat + i * 2500;
    const float* fj = feat + j * 2500;
    for (int c = 0; c < 2500; ++c) acc += fi[c] * fj[c];
    gram[i][j] = acc;
    gram[j][i] = acc;
  }
  __syncthreads();
  // d = sqrt(max(sq_i + sq_j - 2 gram, 0)), zero diagonal (symmetric by construction)
  for (int e = t; e < 1024; e += 256) {
    int i = e >> 5, j = e & 31;
    float d2 = gram[i][i] + gram[j][j] - 2.f * gram[i][j];
    float dd = sqrtf(fmaxf(d2, 0.f));
    if (i == j) dd = 0.f;
    d[i][j] = dd;
  }
  __syncthreads();
  if (t < 32) {
    float s = 0.f;
    for (int j = 0; j < 32; ++j) s += d[t][j];
    avg[t] = s * (1.f / 32.f);
  }
  for (int e = t; e < 1024; e += 256) Hm[e >> 5][e & 31] = 0.f;
  __syncthreads();
  // top-5 smallest per row t (lowest-index tie-break), scatter into H column t
  if (t < 32) {
    unsigned picked = 0;
    float a = avg[t];
    float inv = 1.f / (a * a);
    for (int s = 0; s < 5; ++s) {
      float best = 1e30f;
      int bi = 0;
      for (int j = 0; j < 32; ++j) {
        if (picked & (1u << j)) continue;
        float dv = d[t][j];
        if (dv < best) { best = dv; bi = j; }
      }
      picked |= 1u << bi;
      Hm[bi][t] = expf(-best * best * inv);
    }
  }
  __syncthreads();
  if (t < 32) {
    float se = 0.f, sv = 0.f;
    for (int r = 0; r < 32; ++r) se += Hm[r][t];   // DE: column sum
    for (int c = 0; c < 32; ++c) sv += Hm[t][c];   // DV: row sum
    DE[t] = se;
    dvi[t] = 1.f / sqrtf(sv);
  }
  __syncthreads();
  for (int e = t; e < 1024; e += 256) {
    int i = e >> 5, j = e & 31;
    Hn[i][j] = Hm[i][j] * (1.f / DE[j]);
  }
  __syncthreads();
  // G = dvi_i * (Hn @ H^T) * dvi_j
  for (int e = t; e < 1024; e += 256) {
    int i = e >> 5, j = e & 31;
    float acc = 0.f;
    for (int c = 0; c < 32; ++c) acc += Hn[i][c] * Hm[j][c];
    Gout[(size_t)b * 1024 + e] = dvi[i] * acc * dvi[j];
  }
}

// ---------------- t1 = feat @ hg_w1 + hg_b1 : 256 rows x 512 cols, dot-2500
__global__ void __launch_bounds__(512) hg_mm1_k(const float* __restrict__ ft,
                                                const float* __restrict__ w1,
                                                const float* __restrict__ b1,
                                                float* __restrict__ t1) {
  __shared__ float frow[2500];
  int row = blockIdx.x;  // b*32 + i
  for (int i = threadIdx.x; i < 2500; i += 512) frow[i] = ft[(size_t)row * 2500 + i];
  __syncthreads();
  int j = threadIdx.x;
  float acc = b1[j];
  for (int c = 0; c < 2500; ++c) acc += frow[c] * w1[(size_t)c * 512 + j];
  t1[(size_t)row * 512 + j] = acc;
}

// ---------------- per-sample tail: z=relu(G@t1); t2=z@w2+b2; gout=G@t2; colmean + f2
__global__ void __launch_bounds__(512) hg_tail_k(const float* __restrict__ G,
                                                 const float* __restrict__ t1,
                                                 const float* __restrict__ w2,
                                                 const float* __restrict__ b2,
                                                 const float* __restrict__ f2,
                                                 float* __restrict__ outv) {
  int b = blockIdx.x;
  __shared__ float Gs[32][32];
  __shared__ float z[32][512];
  __shared__ float t2[32][32];
  int t = threadIdx.x;
  for (int e = t; e < 1024; e += 512) Gs[e >> 5][e & 31] = G[(size_t)b * 1024 + e];
  __syncthreads();
  const float* t1b = t1 + (size_t)b * 32 * 512;
  for (int e = t; e < 16384; e += 512) {
    int i = e >> 9, j = e & 511;
    float acc = 0.f;
    for (int c = 0; c < 32; ++c) acc += Gs[i][c] * t1b[c * 512 + j];
    z[i][j] = fmaxf(acc, 0.f);
  }
  __syncthreads();
  for (int e = t; e < 1024; e += 512) {
    int i = e >> 5, j = e & 31;
    float acc = b2[j];
    for (int c = 0; c < 512; ++c) acc += z[i][c] * w2[c * 32 + j];
    t2[i][j] = acc;
  }
  __syncthreads();
  if (t < 32) {
    int j = t;
    float s = 0.f;
    for (int i = 0; i < 32; ++i) {
      float acc = 0.f;
      for (int c = 0; c < 32; ++c) acc += Gs[i][c] * t2[c][j];
      s += acc;
    }
    outv[b * 32 + j] = s * (1.f / 32.f) + f2[b * 32 + j];
  }
}

// ---------------- head: logits = out @ head_w + head_b ; also copy f to tail of d_out
__global__ void __launch_bounds__(256) head_k(const float* __restrict__ outv,
                                              const float* __restrict__ hw,
                                              const float* __restrict__ hb,
                                              const float* __restrict__ f2,
                                              float* __restrict__ dout) {
  int i = blockIdx.x * 256 + threadIdx.x;
  if (i < 8000) {
    int b = i / 1000, j = i % 1000;
    float acc = hb[j];
    for (int c = 0; c < 32; ++c) acc += outv[b * 32 + c] * hw[c * 1000 + j];
    dout[i] = acc;
  }
  if (i < 256) dout[8000 + i] = f2[i];
}

extern "C" void kernel_launch(void* const* d_in, const int* in_sizes, int n_in,
                              void* d_out, int out_size, void* d_ws, size_t ws_size,
                              hipStream_t stream) {
  const float* x     = (const float*)d_in[0];
  const float* xf    = (const float*)d_in[1];
  const float* c1w   = (const float*)d_in[2];
  const float* c1b   = (const float*)d_in[3];
  const float* c2w   = (const float*)d_in[4];
  const float* c2b   = (const float*)d_in[5];
  const float* enc_w = (const float*)d_in[6];
  const float* enc_b = (const float*)d_in[7];
  const float* wq    = (const float*)d_in[8];
  const float* bq    = (const float*)d_in[9];
  const float* wk    = (const float*)d_in[10];
  const float* bk    = (const float*)d_in[11];
  const float* wv    = (const float*)d_in[12];
  const float* bv    = (const float*)d_in[13];
  const float* wo    = (const float*)d_in[14];
  const float* bo    = (const float*)d_in[15];
  const float* dec_w = (const float*)d_in[16];
  const float* dec_b = (const float*)d_in[17];
  const float* w1    = (const float*)d_in[18];
  const float* b1    = (const float*)d_in[19];
  const float* w2    = (const float*)d_in[20];
  const float* b2    = (const float*)d_in[21];
  const float* hw    = (const float*)d_in[22];
  const float* hb    = (const float*)d_in[23];
  float* out = (float*)d_out;

  float* ws   = (float*)d_ws;
  float* h1   = ws;                    // 8*64*150*150 = 11,520,000 floats
  float* ftb  = h1 + 11520000;         // 8*32*2500    =    640,000
  float* f2   = ftb + 640000;          // 8*32         =        256
  float* G    = f2 + 256;              // 8*32*32      =      8,192
  float* t1   = G + 8192;              // 8*32*512     =    131,072
  float* outv = t1 + 131072;           // 8*32         =        256

  conv1_k<<<(8 * 64 * 150 * 150 + 255) / 256, 256, 0, stream>>>(x, c1w, c1b, h1);
  dim3 g2(256, 10);
  conv2_k<<<g2, 256, 0, stream>>>(h1, c2w, c2b, ftb);
  feat_k<<<1, 512, 0, stream>>>(xf, enc_w, enc_b, wq, bq, wk, bk, wv, bv, wo, bo,
                                dec_w, dec_b, f2);
  hg_G_k<<<8, 256, 0, stream>>>(ftb, G);
  hg_mm1_k<<<256, 512, 0, stream>>>(ftb, w1, b1, t1);
  hg_tail_k<<<8, 512, 0, stream>>>(G, t1, w2, b2, f2, outv);
  head_k<<<32, 256, 0, stream>>>(outv, hw, hb, f2, out);
}

// Round 2
// 895.643 us; speedup vs baseline: 1.9386x; 1.9386x over previous
//
#include <hip/hip_runtime.h>
#include <hip/hip_bf16.h>

#define RFL(x) __builtin_amdgcn_readfirstlane(x)

// ---------------- conv1: [8,3,448,448] (chan-reversed) -> [8,64,150,150], 5x5 s3 p2, ReLU
// lane = pixel (coalesced), wave = 16-o group (weights via s_load)
__global__ void __launch_bounds__(256) conv1_k(const float* __restrict__ x,
                                               const float* __restrict__ w,
                                               const float* __restrict__ bias,
                                               float* __restrict__ out) {
  int b = blockIdx.x / 352;
  int pblk = blockIdx.x % 352;
  int lane = threadIdx.x & 63;
  int ob = RFL(threadIdx.x >> 6) * 16;
  int pixel = pblk * 64 + lane;
  bool pv = pixel < 22500;
  int py = pixel / 150, px = pixel % 150;
  int iy0 = py * 3 - 2, ix0 = px * 3 - 2;
  float acc[16];
#pragma unroll
  for (int u = 0; u < 16; ++u) acc[u] = bias[ob + u];
  for (int c = 0; c < 3; ++c) {
    const float* xp = x + (size_t)(b * 3 + (2 - c)) * 200704;  // 448*448
    const float* wp = w + c * 25;
#pragma unroll
    for (int ky = 0; ky < 5; ++ky) {
      int iy = iy0 + ky;
      bool rok = (iy >= 0) & (iy < 448);
      const float* xrow = xp + iy * 448;
#pragma unroll
      for (int kx = 0; kx < 5; ++kx) {
        int ix = ix0 + kx;
        bool ok = pv & rok & (ix >= 0) & (ix < 448);
        float xv = ok ? xrow[ix] : 0.f;
#pragma unroll
        for (int u = 0; u < 16; ++u)
          acc[u] += xv * wp[(ob + u) * 75 + ky * 5 + kx];  // uniform -> s_load
      }
    }
  }
  if (pv) {
#pragma unroll
    for (int u = 0; u < 16; ++u)
      out[(size_t)(b * 64 + ob + u) * 22500 + pixel] = fmaxf(acc[u], 0.f);
  }
}

// ---------------- conv2: [8,64,150,150] -> [8,32,50,50], 5x5 s3 p2, ReLU
// lane = pixel, wave = 8-o group
__global__ void __launch_bounds__(256) conv2_k(const float* __restrict__ h1,
                                               const float* __restrict__ w,
                                               const float* __restrict__ bias,
                                               float* __restrict__ ft) {
  int b = blockIdx.x / 40;
  int pblk = blockIdx.x % 40;
  int lane = threadIdx.x & 63;
  int ob = RFL(threadIdx.x >> 6) * 8;
  int pixel = pblk * 64 + lane;
  bool pv = pixel < 2500;
  int py = pixel / 50, px = pixel % 50;
  int iy0 = py * 3 - 2, ix0 = px * 3 - 2;
  float acc[8];
#pragma unroll
  for (int u = 0; u < 8; ++u) acc[u] = bias[ob + u];
  for (int c = 0; c < 64; ++c) {
    const float* hp = h1 + (size_t)(b * 64 + c) * 22500;
    const float* wp = w + c * 25;
#pragma unroll
    for (int ky = 0; ky < 5; ++ky) {
      int iy = iy0 + ky;
      bool rok = (iy >= 0) & (iy < 150);
      const float* hrow = hp + iy * 150;
#pragma unroll
      for (int kx = 0; kx < 5; ++kx) {
        int ix = ix0 + kx;
        bool ok = pv & rok & (ix >= 0) & (ix < 150);
        float xv = ok ? hrow[ix] : 0.f;
#pragma unroll
        for (int u = 0; u < 8; ++u)
          acc[u] += xv * wp[(ob + u) * 1600 + ky * 5 + kx];  // uniform -> s_load
      }
    }
  }
  if (pv) {
#pragma unroll
    for (int u = 0; u < 8; ++u)
      ft[(size_t)(b * 32 + ob + u) * 2500 + pixel] = fmaxf(acc[u], 0.f);
  }
}

// ---------------- transpose ft [b][32][2500] -> ftT [b][2500][32]
__global__ void __launch_bounds__(256) transpose_k(const float* __restrict__ ft,
                                                   float* __restrict__ ftT) {
  int idx = blockIdx.x * 256 + threadIdx.x;
  if (idx >= 640000) return;
  int o = idx & 31;
  int rest = idx >> 5;  // b*2500 + p
  int p = rest % 2500;
  int b = rest / 2500;
  ftT[idx] = ft[(size_t)(b * 32 + o) * 2500 + p];
}

// ---------------- feature branch kernels
__global__ void __launch_bounds__(512) fk_enc(const float* __restrict__ xf,
                                              const float* __restrict__ ew,
                                              const float* __restrict__ eb,
                                              float* __restrict__ f) {
  int b = blockIdx.x, j = threadIdx.x;
  float acc = eb[j];
  for (int c = 0; c < 36; ++c) acc += xf[b * 36 + c] * ew[c * 512 + j];
  f[b * 512 + j] = fmaxf(acc, 0.f);
}

__global__ void __launch_bounds__(512) fk_qkv(const float* __restrict__ f,
                                              const float* __restrict__ wq, const float* __restrict__ bq,
                                              const float* __restrict__ wk, const float* __restrict__ bk,
                                              const float* __restrict__ wv, const float* __restrict__ bv,
                                              float* __restrict__ qkv) {
  int b = blockIdx.x, m = blockIdx.y, j = threadIdx.x;
  const float* W = (m == 0) ? wq : (m == 1) ? wk : wv;
  const float* B = (m == 0) ? bq : (m == 1) ? bk : bv;
  float acc = B[j];
  for (int c = 0; c < 512; ++c) acc += f[b * 512 + c] * W[(size_t)c * 512 + j];
  qkv[(m * 8 + b) * 512 + j] = acc;
}

__global__ void __launch_bounds__(256) fk_attn(const float* __restrict__ qkv,
                                               float* __restrict__ ao) {
  __shared__ float att[2][8][8];
  int t = threadIdx.x;
  const float* q = qkv;
  const float* kk = qkv + 4096;
  const float* v = qkv + 8192;
  if (t < 128) {
    int h = t >> 6, b = (t >> 3) & 7, c = t & 7;
    float acc = 0.f;
    for (int d = 0; d < 256; ++d)
      acc += q[b * 512 + h * 256 + d] * kk[c * 512 + h * 256 + d];
    att[h][b][c] = acc * (1.f / 16.f);
  }
  __syncthreads();
  if (t < 16) {
    int h = t >> 3, b = t & 7;
    float mx = -1e30f;
    for (int c = 0; c < 8; ++c) mx = fmaxf(mx, att[h][b][c]);
    float e[8], s = 0.f;
    for (int c = 0; c < 8; ++c) { e[c] = expf(att[h][b][c] - mx); s += e[c]; }
    for (int c = 0; c < 8; ++c) att[h][b][c] = e[c] / s;
  }
  __syncthreads();
  for (int i = t; i < 4096; i += 256) {
    int b = i >> 9, j = i & 511, h = j >> 8;
    float acc = 0.f;
#pragma unroll
    for (int c = 0; c < 8; ++c) acc += att[h][b][c] * v[c * 512 + j];
    ao[b * 512 + j] = acc;
  }
}

__global__ void __launch_bounds__(512) fk_odec(const float* __restrict__ ao,
                                               const float* __restrict__ wo, const float* __restrict__ bo,
                                               const float* __restrict__ dw, const float* __restrict__ db,
                                               float* __restrict__ f2) {
  __shared__ float os[512];
  int b = blockIdx.x, j = threadIdx.x;
  float acc = bo[j];
  for (int c = 0; c < 512; ++c) acc += ao[b * 512 + c] * wo[(size_t)c * 512 + j];
  os[j] = acc;
  __syncthreads();
  if (j < 32) {
    float a2 = db[j];
    for (int c = 0; c < 512; ++c) a2 += os[c] * dw[c * 32 + j];
    f2[b * 32 + j] = fmaxf(a2, 0.f);
  }
}

// ---------------- hypergraph G per sample (gram from ftT; rest in LDS)
__global__ void __launch_bounds__(256) hg_G_k(const float* __restrict__ ftT,
                                              float* __restrict__ Gout) {
  int b = blockIdx.x;
  const float* S = ftT + (size_t)b * 80000;  // [2500][32]
  __shared__ float gram[32][32];
  __shared__ float d[32][32];
  __shared__ float avg[32];
  __shared__ float Hm[32][32];
  __shared__ float Hn[32][32];
  __shared__ float DE[32];
  __shared__ float dvi[32];
  int t = threadIdx.x;
  {
    int i = t >> 3;
    int j0 = (t & 7) * 4;
    float a0 = 0.f, a1 = 0.f, a2 = 0.f, a3 = 0.f;
    for (int p = 0; p < 2500; ++p) {
      float ai = S[p * 32 + i];
      const float4 bj = *(const float4*)(S + p * 32 + j0);
      a0 += ai * bj.x; a1 += ai * bj.y; a2 += ai * bj.z; a3 += ai * bj.w;
    }
    gram[i][j0] = a0; gram[i][j0 + 1] = a1; gram[i][j0 + 2] = a2; gram[i][j0 + 3] = a3;
  }
  __syncthreads();
  for (int e = t; e < 1024; e += 256) {
    int i = e >> 5, j = e & 31;
    float d2 = gram[i][i] + gram[j][j] - 2.f * gram[i][j];
    float dd = sqrtf(fmaxf(d2, 0.f));
    if (i == j) dd = 0.f;
    d[i][j] = dd;
  }
  __syncthreads();
  if (t < 32) {
    float s = 0.f;
    for (int j = 0; j < 32; ++j) s += d[t][j];
    avg[t] = s * (1.f / 32.f);
  }
  for (int e = t; e < 1024; e += 256) Hm[e >> 5][e & 31] = 0.f;
  __syncthreads();
  if (t < 32) {
    unsigned picked = 0;
    float a = avg[t];
    float inv = 1.f / (a * a);
    for (int s = 0; s < 5; ++s) {
      float best = 1e30f;
      int bi = 0;
      for (int j = 0; j < 32; ++j) {
        if (picked & (1u << j)) continue;
        float dv = d[t][j];
        if (dv < best) { best = dv; bi = j; }
      }
      picked |= 1u << bi;
      Hm[bi][t] = expf(-best * best * inv);
    }
  }
  __syncthreads();
  if (t < 32) {
    float se = 0.f, sv = 0.f;
    for (int r = 0; r < 32; ++r) se += Hm[r][t];
    for (int c = 0; c < 32; ++c) sv += Hm[t][c];
    DE[t] = se;
    dvi[t] = 1.f / sqrtf(sv);
  }
  __syncthreads();
  for (int e = t; e < 1024; e += 256) {
    int i = e >> 5, j = e & 31;
    Hn[i][j] = Hm[i][j] * (1.f / DE[j]);
  }
  __syncthreads();
  for (int e = t; e < 1024; e += 256) {
    int i = e >> 5, j = e & 31;
    float acc = 0.f;
#pragma unroll
    for (int c = 0; c < 32; ++c) acc += Hn[i][c] * Hm[j][c];
    Gout[(size_t)b * 1024 + e] = dvi[i] * acc * dvi[j];
  }
}

// ---------------- t1 partials: ft[256,2500] @ w1[2500,512], K split 4 ways
__global__ void __launch_bounds__(512) hg_mm1_k(const float* __restrict__ ft,
                                                const float* __restrict__ w1,
                                                float* __restrict__ part) {
  int rg = blockIdx.x;   // 0..31 (8 rows each)
  int ch = blockIdx.y;   // 0..3  (625 c each)
  int j = threadIdx.x;
  int r0 = rg * 8;
  int c0 = ch * 625;
  float acc[8];
#pragma unroll
  for (int r = 0; r < 8; ++r) acc[r] = 0.f;
  for (int c = c0; c < c0 + 625; ++c) {
    float wv = w1[(size_t)c * 512 + j];
#pragma unroll
    for (int r = 0; r < 8; ++r)
      acc[r] += ft[(size_t)(r0 + r) * 2500 + c] * wv;  // uniform -> s_load
  }
#pragma unroll
  for (int r = 0; r < 8; ++r)
    part[((size_t)ch * 256 + r0 + r) * 512 + j] = acc[r];
}

__global__ void __launch_bounds__(256) mm1_comb_k(const float* __restrict__ part,
                                                  const float* __restrict__ b1,
                                                  float* __restrict__ t1) {
  int idx = blockIdx.x * 256 + threadIdx.x;
  if (idx >= 131072) return;
  int j = idx & 511;
  t1[idx] = part[idx] + part[131072 + idx] + part[262144 + idx] + part[393216 + idx] + b1[j];
}

// ---------------- per-sample tail: z=relu(G@t1); t2=z@w2+b2; colmean(G@t2) + f2
__global__ void __launch_bounds__(512) hg_tail_k(const float* __restrict__ G,
                                                 const float* __restrict__ t1,
                                                 const float* __restrict__ w2,
                                                 const float* __restrict__ b2,
                                                 const float* __restrict__ f2,
                                                 float* __restrict__ outv) {
  int b = blockIdx.x;
  __shared__ float zs[32][512];
  __shared__ float t2s[32][32];
  int t = threadIdx.x;
  const float* Gb = G + b * 1024;
  const float* t1b = t1 + b * 16384;
  {
    int j = t;
    float acc[32];
#pragma unroll
    for (int i = 0; i < 32; ++i) acc[i] = 0.f;
    for (int c = 0; c < 32; ++c) {
      float tv = t1b[c * 512 + j];
#pragma unroll
      for (int i = 0; i < 32; ++i) acc[i] += Gb[i * 32 + c] * tv;  // G uniform -> s_load
    }
#pragma unroll
    for (int i = 0; i < 32; ++i) zs[i][j] = fmaxf(acc[i], 0.f);
  }
  __syncthreads();
#pragma unroll
  for (int e2 = 0; e2 < 2; ++e2) {
    int e = t + e2 * 512;
    int i = e >> 5, jj = e & 31;
    float acc = b2[jj];
    for (int c = 0; c < 512; ++c) acc += zs[i][c] * w2[c * 32 + jj];
    t2s[i][jj] = acc;
  }
  __syncthreads();
  if (t < 32) {
    int j = t;
    float s = 0.f;
    for (int i = 0; i < 32; ++i) {
      float acc = 0.f;
#pragma unroll
      for (int c = 0; c < 32; ++c) acc += Gb[i * 32 + c] * t2s[c][j];
      s += acc;
    }
    outv[b * 32 + j] = s * (1.f / 32.f) + f2[b * 32 + j];
  }
}

// ---------------- head: logits = out @ head_w + head_b ; copy f2 to tail
__global__ void __launch_bounds__(256) head_k(const float* __restrict__ outv,
                                              const float* __restrict__ hw,
                                              const float* __restrict__ hb,
                                              const float* __restrict__ f2,
                                              float* __restrict__ dout) {
  int i = blockIdx.x * 256 + threadIdx.x;
  if (i < 8000) {
    int b = i / 1000, j = i % 1000;
    float acc = hb[j];
#pragma unroll
    for (int c = 0; c < 32; ++c) acc += outv[b * 32 + c] * hw[c * 1000 + j];
    dout[i] = acc;
  }
  if (i < 256) dout[8000 + i] = f2[i];
}

extern "C" void kernel_launch(void* const* d_in, const int* in_sizes, int n_in,
                              void* d_out, int out_size, void* d_ws, size_t ws_size,
                              hipStream_t stream) {
  const float* x     = (const float*)d_in[0];
  const float* xf    = (const float*)d_in[1];
  const float* c1w   = (const float*)d_in[2];
  const float* c1b   = (const float*)d_in[3];
  const float* c2w   = (const float*)d_in[4];
  const float* c2b   = (const float*)d_in[5];
  const float* enc_w = (const float*)d_in[6];
  const float* enc_b = (const float*)d_in[7];
  const float* wq    = (const float*)d_in[8];
  const float* bq    = (const float*)d_in[9];
  const float* wk    = (const float*)d_in[10];
  const float* bk    = (const float*)d_in[11];
  const float* wv    = (const float*)d_in[12];
  const float* bv    = (const float*)d_in[13];
  const float* wo    = (const float*)d_in[14];
  const float* bo    = (const float*)d_in[15];
  const float* dec_w = (const float*)d_in[16];
  const float* dec_b = (const float*)d_in[17];
  const float* w1    = (const float*)d_in[18];
  const float* b1    = (const float*)d_in[19];
  const float* w2    = (const float*)d_in[20];
  const float* b2    = (const float*)d_in[21];
  const float* hw    = (const float*)d_in[22];
  const float* hb    = (const float*)d_in[23];
  float* out = (float*)d_out;

  float* ws = (float*)d_ws;
  // region layout (floats). h1 [0,11.52M) is dead after conv2; reuse it.
  float* h1   = ws;                  // 11,520,000
  float* ftb  = ws + 11520000;       //    640,000
  float* ftT  = ws;                  //    640,000 (reuses h1)
  float* t1   = ws + 640000;         //    131,072
  float* part = ws + 771072;         //    524,288
  float* f    = ws + 1295360;        //      4,096
  float* qkv  = ws + 1299456;        //     12,288
  float* ao   = ws + 1311744;        //      4,096
  float* f2   = ws + 1315840;        //        256
  float* outv = ws + 1316096;        //        256
  float* G    = ws + 1316352;        //      8,192

  conv1_k<<<8 * 352, 256, 0, stream>>>(x, c1w, c1b, h1);
  conv2_k<<<8 * 40, 256, 0, stream>>>(h1, c2w, c2b, ftb);
  transpose_k<<<2500, 256, 0, stream>>>(ftb, ftT);

  fk_enc<<<8, 512, 0, stream>>>(xf, enc_w, enc_b, f);
  dim3 gq(8, 3);
  fk_qkv<<<gq, 512, 0, stream>>>(f, wq, bq, wk, bk, wv, bv, qkv);
  fk_attn<<<1, 256, 0, stream>>>(qkv, ao);
  fk_odec<<<8, 512, 0, stream>>>(ao, wo, bo, dec_w, dec_b, f2);

  hg_G_k<<<8, 256, 0, stream>>>(ftT, G);
  dim3 gm(32, 4);
  hg_mm1_k<<<gm, 512, 0, stream>>>(ftb, w1, part);
  mm1_comb_k<<<512, 256, 0, stream>>>(part, b1, t1);
  hg_tail_k<<<8, 512, 0, stream>>>(G, t1, w2, b2, f2, outv);
  head_k<<<32, 256, 0, stream>>>(outv, hw, hb, f2, out);
}

// Round 3
// 574.880 us; speedup vs baseline: 3.0203x; 1.5580x over previous
//
#include <hip/hip_runtime.h>
#include <hip/hip_bf16.h>

#define RFL(x) __builtin_amdgcn_readfirstlane(x)

// ---------------- conv1: [8,3,448,448] (chan-reversed) -> [8,64,150,150], 5x5 s3 p2, ReLU
// block = (b, py). LDS halo tile, wave = 16-o group, lane = px.
__global__ void __launch_bounds__(256) conv1_k(const float* __restrict__ x,
                                               const float* __restrict__ w,
                                               const float* __restrict__ bias,
                                               float* __restrict__ out) {
  __shared__ float xt[3][5][456];   // col = ix+2, ix in [-2,449]
  int b = blockIdx.x / 150;
  int py = blockIdx.x % 150;
  int t = threadIdx.x;
  int iy0 = py * 3 - 2;
  for (int e = t; e < 6840; e += 256) {
    int c = e / 2280;
    int rest = e % 2280;
    int r = rest / 456;
    int col = rest % 456;
    int iy = iy0 + r;
    int ix = col - 2;
    float v = 0.f;
    if (iy >= 0 && iy < 448 && ix >= 0 && ix < 448)
      v = x[((size_t)(b * 3 + (2 - c)) * 448 + iy) * 448 + ix];
    xt[c][r][col] = v;
  }
  __syncthreads();
  int lane = t & 63;
  int ob = RFL(t >> 6) * 16;
  for (int sub = 0; sub < 3; ++sub) {
    int px = sub * 64 + lane;
    float acc[16];
#pragma unroll
    for (int u = 0; u < 16; ++u) acc[u] = bias[ob + u];
#pragma unroll
    for (int c = 0; c < 3; ++c)
#pragma unroll
      for (int ky = 0; ky < 5; ++ky)
#pragma unroll
        for (int kx = 0; kx < 5; ++kx) {
          float xv = xt[c][ky][px * 3 + kx];
#pragma unroll
          for (int u = 0; u < 16; ++u)
            acc[u] += xv * w[(ob + u) * 75 + c * 25 + ky * 5 + kx];  // s_load
        }
    if (px < 150) {
#pragma unroll
      for (int u = 0; u < 16; ++u)
        out[(size_t)(b * 64 + ob + u) * 22500 + py * 150 + px] = fmaxf(acc[u], 0.f);
    }
  }
}

// ---------------- conv2: [8,64,150,150] -> [8,32,50,50], 5x5 s3 p2, ReLU
// block = (b, py). 4 chunks of 16 c staged in LDS. Writes ft AND ftT (transposed).
__global__ void __launch_bounds__(256) conv2_k(const float* __restrict__ h1,
                                               const float* __restrict__ w,
                                               const float* __restrict__ bias,
                                               float* __restrict__ ft,
                                               float* __restrict__ ftT) {
  __shared__ float ht[16][5][152];  // col = ix+2, ix in [-2,149]
  __shared__ float tile[32][51];
  int b = blockIdx.x / 50;
  int py = blockIdx.x % 50;
  int t = threadIdx.x;
  int lane = t & 63;
  int ob = RFL(t >> 6) * 8;
  int px = lane;                    // 0..49 valid
  int iy0 = py * 3 - 2;
  float acc[8];
#pragma unroll
  for (int u = 0; u < 8; ++u) acc[u] = 0.f;
  for (int ch = 0; ch < 4; ++ch) {
    __syncthreads();
    for (int e = t; e < 12160; e += 256) {
      int c = e / 760;
      int rest = e % 760;
      int r = rest / 152;
      int col = rest % 152;
      int iy = iy0 + r;
      int ix = col - 2;
      float v = 0.f;
      if (iy >= 0 && iy < 150 && ix >= 0 && ix < 150)
        v = h1[((size_t)(b * 64 + ch * 16 + c) * 150 + iy) * 150 + ix];
      ht[c][r][col] = v;
    }
    __syncthreads();
    for (int c = 0; c < 16; ++c) {
#pragma unroll
      for (int ky = 0; ky < 5; ++ky)
#pragma unroll
        for (int kx = 0; kx < 5; ++kx) {
          float xv = ht[c][ky][px * 3 + kx];
#pragma unroll
          for (int u = 0; u < 8; ++u)
            acc[u] += xv * w[(ob + u) * 1600 + (ch * 16 + c) * 25 + ky * 5 + kx];
        }
    }
  }
  if (px < 50) {
#pragma unroll
    for (int u = 0; u < 8; ++u)
      tile[ob + u][px] = fmaxf(acc[u] + bias[ob + u], 0.f);
  }
  __syncthreads();
  for (int e = t; e < 1600; e += 256) {
    int o = e / 50, p = e % 50;
    ft[(size_t)(b * 32 + o) * 2500 + py * 50 + p] = tile[o][p];
  }
  for (int e = t; e < 1600; e += 256) {
    int p = e >> 5, o = e & 31;
    ftT[((size_t)b * 2500 + py * 50 + p) * 32 + o] = tile[o][p];
  }
}

// ---------------- feature branch: enc + qkv fused (per-b block)
__global__ void __launch_bounds__(512) fk_encqkv(const float* __restrict__ xf,
                                                 const float* __restrict__ ew, const float* __restrict__ eb,
                                                 const float* __restrict__ wq, const float* __restrict__ bq,
                                                 const float* __restrict__ wk, const float* __restrict__ bk,
                                                 const float* __restrict__ wv, const float* __restrict__ bv,
                                                 float* __restrict__ qkv) {
  __shared__ float fs[512];
  int b = blockIdx.x, j = threadIdx.x;
  float acc = eb[j];
  for (int c = 0; c < 36; ++c) acc += xf[b * 36 + c] * ew[c * 512 + j];
  fs[j] = fmaxf(acc, 0.f);
  __syncthreads();
  float aq = bq[j], ak = bk[j], av = bv[j];
  for (int c = 0; c < 512; ++c) {
    float fv = fs[c];
    aq += fv * wq[c * 512 + j];
    ak += fv * wk[c * 512 + j];
    av += fv * wv[c * 512 + j];
  }
  qkv[b * 512 + j] = aq;
  qkv[4096 + b * 512 + j] = ak;
  qkv[8192 + b * 512 + j] = av;
}

__global__ void __launch_bounds__(256) fk_attn(const float* __restrict__ qkv,
                                               float* __restrict__ ao) {
  __shared__ float att[2][8][8];
  int t = threadIdx.x;
  const float* q = qkv;
  const float* kk = qkv + 4096;
  const float* v = qkv + 8192;
  if (t < 128) {
    int h = t >> 6, b = (t >> 3) & 7, c = t & 7;
    float acc = 0.f;
    for (int d = 0; d < 256; ++d)
      acc += q[b * 512 + h * 256 + d] * kk[c * 512 + h * 256 + d];
    att[h][b][c] = acc * (1.f / 16.f);
  }
  __syncthreads();
  if (t < 16) {
    int h = t >> 3, b = t & 7;
    float mx = -1e30f;
    for (int c = 0; c < 8; ++c) mx = fmaxf(mx, att[h][b][c]);
    float e[8], s = 0.f;
    for (int c = 0; c < 8; ++c) { e[c] = expf(att[h][b][c] - mx); s += e[c]; }
    for (int c = 0; c < 8; ++c) att[h][b][c] = e[c] / s;
  }
  __syncthreads();
  for (int i = t; i < 4096; i += 256) {
    int b = i >> 9, j = i & 511, h = j >> 8;
    float acc = 0.f;
#pragma unroll
    for (int c = 0; c < 8; ++c) acc += att[h][b][c] * v[c * 512 + j];
    ao[b * 512 + j] = acc;
  }
}

__global__ void __launch_bounds__(512) fk_odec(const float* __restrict__ ao,
                                               const float* __restrict__ wo, const float* __restrict__ bo,
                                               const float* __restrict__ dw, const float* __restrict__ db,
                                               float* __restrict__ f2) {
  __shared__ float os[512];
  int b = blockIdx.x, j = threadIdx.x;
  float acc = bo[j];
  for (int c = 0; c < 512; ++c) acc += ao[b * 512 + c] * wo[(size_t)c * 512 + j];
  os[j] = acc;
  __syncthreads();
  if (j < 32) {
    float a2 = db[j];
    for (int c = 0; c < 512; ++c) a2 += os[c] * dw[c * 32 + j];
    f2[b * 32 + j] = fmaxf(a2, 0.f);
  }
}

// ---------------- hypergraph G per sample (gram from ftT; rest in LDS)
__global__ void __launch_bounds__(256) hg_G_k(const float* __restrict__ ftT,
                                              float* __restrict__ Gout) {
  int b = blockIdx.x;
  const float* S = ftT + (size_t)b * 80000;  // [2500][32]
  __shared__ float gram[32][32];
  __shared__ float d[32][32];
  __shared__ float avg[32];
  __shared__ float Hm[32][32];
  __shared__ float Hn[32][32];
  __shared__ float DE[32];
  __shared__ float dvi[32];
  int t = threadIdx.x;
  {
    int i = t >> 3;
    int j0 = (t & 7) * 4;
    float a0 = 0.f, a1 = 0.f, a2 = 0.f, a3 = 0.f;
    for (int p = 0; p < 2500; ++p) {
      float ai = S[p * 32 + i];
      const float4 bj = *(const float4*)(S + p * 32 + j0);
      a0 += ai * bj.x; a1 += ai * bj.y; a2 += ai * bj.z; a3 += ai * bj.w;
    }
    gram[i][j0] = a0; gram[i][j0 + 1] = a1; gram[i][j0 + 2] = a2; gram[i][j0 + 3] = a3;
  }
  __syncthreads();
  for (int e = t; e < 1024; e += 256) {
    int i = e >> 5, j = e & 31;
    float d2 = gram[i][i] + gram[j][j] - 2.f * gram[i][j];
    float dd = sqrtf(fmaxf(d2, 0.f));
    if (i == j) dd = 0.f;
    d[i][j] = dd;
  }
  __syncthreads();
  if (t < 32) {
    float s = 0.f;
    for (int j = 0; j < 32; ++j) s += d[t][j];
    avg[t] = s * (1.f / 32.f);
  }
  for (int e = t; e < 1024; e += 256) Hm[e >> 5][e & 31] = 0.f;
  __syncthreads();
  if (t < 32) {
    unsigned picked = 0;
    float a = avg[t];
    float inv = 1.f / (a * a);
    for (int s = 0; s < 5; ++s) {
      float best = 1e30f;
      int bi = 0;
      for (int j = 0; j < 32; ++j) {
        if (picked & (1u << j)) continue;
        float dv = d[t][j];
        if (dv < best) { best = dv; bi = j; }
      }
      picked |= 1u << bi;
      Hm[bi][t] = expf(-best * best * inv);
    }
  }
  __syncthreads();
  if (t < 32) {
    float se = 0.f, sv = 0.f;
    for (int r = 0; r < 32; ++r) se += Hm[r][t];
    for (int c = 0; c < 32; ++c) sv += Hm[t][c];
    DE[t] = se;
    dvi[t] = 1.f / sqrtf(sv);
  }
  __syncthreads();
  for (int e = t; e < 1024; e += 256) {
    int i = e >> 5, j = e & 31;
    Hn[i][j] = Hm[i][j] * (1.f / DE[j]);
  }
  __syncthreads();
  for (int e = t; e < 1024; e += 256) {
    int i = e >> 5, j = e & 31;
    float acc = 0.f;
#pragma unroll
    for (int c = 0; c < 32; ++c) acc += Hn[i][c] * Hm[j][c];
    Gout[(size_t)b * 1024 + e] = dvi[i] * acc * dvi[j];
  }
}

// ---------------- t1 partials: ft[256,2500] @ w1[2500,512], 16 rowgroups x 16 k-chunks
__global__ void __launch_bounds__(512) hg_mm1_k(const float* __restrict__ ft,
                                                const float* __restrict__ w1,
                                                float* __restrict__ part) {
  int rg = blockIdx.x;   // 0..15 (16 rows each)
  int ch = blockIdx.y;   // 0..15
  int j = threadIdx.x;
  int r0 = rg * 16;
  int c0 = ch * 156 + min(ch, 4);
  int cn = 156 + (ch < 4 ? 1 : 0);
  float acc[16];
#pragma unroll
  for (int r = 0; r < 16; ++r) acc[r] = 0.f;
#pragma unroll 4
  for (int c = c0; c < c0 + cn; ++c) {
    float wv = w1[(size_t)c * 512 + j];
#pragma unroll
    for (int r = 0; r < 16; ++r)
      acc[r] += ft[(size_t)(r0 + r) * 2500 + c] * wv;  // uniform -> s_load
  }
#pragma unroll
  for (int r = 0; r < 16; ++r)
    part[(size_t)ch * 131072 + (r0 + r) * 512 + j] = acc[r];
}

__global__ void __launch_bounds__(256) mm1_comb_k(const float* __restrict__ part,
                                                  const float* __restrict__ b1,
                                                  float* __restrict__ t1) {
  int idx = blockIdx.x * 256 + threadIdx.x;
  if (idx >= 131072) return;
  float s = b1[idx & 511];
#pragma unroll
  for (int ch = 0; ch < 16; ++ch) s += part[(size_t)ch * 131072 + idx];
  t1[idx] = s;
}

// ---------------- per-sample tail: z=relu(G@t1); t2=z@w2+b2; colmean(G@t2) + f2
__global__ void __launch_bounds__(512) hg_tail_k(const float* __restrict__ G,
                                                 const float* __restrict__ t1,
                                                 const float* __restrict__ w2,
                                                 const float* __restrict__ b2,
                                                 const float* __restrict__ f2,
                                                 float* __restrict__ outv) {
  int b = blockIdx.x;
  __shared__ float zs[32][512];
  __shared__ float t2s[32][32];
  int t = threadIdx.x;
  const float* Gb = G + b * 1024;
  const float* t1b = t1 + b * 16384;
  {
    int j = t;
    float acc[32];
#pragma unroll
    for (int i = 0; i < 32; ++i) acc[i] = 0.f;
    for (int c = 0; c < 32; ++c) {
      float tv = t1b[c * 512 + j];
#pragma unroll
      for (int i = 0; i < 32; ++i) acc[i] += Gb[i * 32 + c] * tv;  // G uniform -> s_load
    }
#pragma unroll
    for (int i = 0; i < 32; ++i) zs[i][j] = fmaxf(acc[i], 0.f);
  }
  __syncthreads();
#pragma unroll
  for (int e2 = 0; e2 < 2; ++e2) {
    int e = t + e2 * 512;
    int i = e >> 5, jj = e & 31;
    float acc = b2[jj];
    for (int c = 0; c < 512; ++c) acc += zs[i][c] * w2[c * 32 + jj];
    t2s[i][jj] = acc;
  }
  __syncthreads();
  if (t < 32) {
    int j = t;
    float s = 0.f;
    for (int i = 0; i < 32; ++i) {
      float acc = 0.f;
#pragma unroll
      for (int c = 0; c < 32; ++c) acc += Gb[i * 32 + c] * t2s[c][j];
      s += acc;
    }
    outv[b * 32 + j] = s * (1.f / 32.f) + f2[b * 32 + j];
  }
}

// ---------------- head: logits = out @ head_w + head_b ; copy f2 to tail
__global__ void __launch_bounds__(256) head_k(const float* __restrict__ outv,
                                              const float* __restrict__ hw,
                                              const float* __restrict__ hb,
                                              const float* __restrict__ f2,
                                              float* __restrict__ dout) {
  int i = blockIdx.x * 256 + threadIdx.x;
  if (i < 8000) {
    int b = i / 1000, j = i % 1000;
    float acc = hb[j];
#pragma unroll
    for (int c = 0; c < 32; ++c) acc += outv[b * 32 + c] * hw[c * 1000 + j];
    dout[i] = acc;
  }
  if (i < 256) dout[8000 + i] = f2[i];
}

extern "C" void kernel_launch(void* const* d_in, const int* in_sizes, int n_in,
                              void* d_out, int out_size, void* d_ws, size_t ws_size,
                              hipStream_t stream) {
  const float* x     = (const float*)d_in[0];
  const float* xf    = (const float*)d_in[1];
  const float* c1w   = (const float*)d_in[2];
  const float* c1b   = (const float*)d_in[3];
  const float* c2w   = (const float*)d_in[4];
  const float* c2b   = (const float*)d_in[5];
  const float* enc_w = (const float*)d_in[6];
  const float* enc_b = (const float*)d_in[7];
  const float* wq    = (const float*)d_in[8];
  const float* bq    = (const float*)d_in[9];
  const float* wk    = (const float*)d_in[10];
  const float* bk    = (const float*)d_in[11];
  const float* wv    = (const float*)d_in[12];
  const float* bv    = (const float*)d_in[13];
  const float* wo    = (const float*)d_in[14];
  const float* bo    = (const float*)d_in[15];
  const float* dec_w = (const float*)d_in[16];
  const float* dec_b = (const float*)d_in[17];
  const float* w1    = (const float*)d_in[18];
  const float* b1    = (const float*)d_in[19];
  const float* w2    = (const float*)d_in[20];
  const float* b2    = (const float*)d_in[21];
  const float* hw    = (const float*)d_in[22];
  const float* hb    = (const float*)d_in[23];
  float* out = (float*)d_out;

  float* ws = (float*)d_ws;
  // layout (floats):
  float* h1   = ws;                  // [0, 11,520,000)  dead after conv2
  float* ftb  = ws + 11520000;       // 640,000
  float* ftT  = ws + 12160000;       // 640,000
  float* qkv  = ws + 12800000;       // 12,288
  float* ao   = ws + 12812288;       // 4,096
  float* f2   = ws + 12816384;       // 256
  float* outv = ws + 12816640;       // 256
  float* G    = ws + 12816896;       // 8,192  -> ends 12,825,088 (51.3 MB)
  // overlays on dead h1 region (used only after conv2):
  float* part = ws;                  // 2,097,152
  float* t1   = ws + 2097152;        // 131,072

  conv1_k<<<8 * 150, 256, 0, stream>>>(x, c1w, c1b, h1);
  conv2_k<<<8 * 50, 256, 0, stream>>>(h1, c2w, c2b, ftb, ftT);

  fk_encqkv<<<8, 512, 0, stream>>>(xf, enc_w, enc_b, wq, bq, wk, bk, wv, bv, qkv);
  fk_attn<<<1, 256, 0, stream>>>(qkv, ao);
  fk_odec<<<8, 512, 0, stream>>>(ao, wo, bo, dec_w, dec_b, f2);

  hg_G_k<<<8, 256, 0, stream>>>(ftT, G);
  dim3 gm(16, 16);
  hg_mm1_k<<<gm, 512, 0, stream>>>(ftb, w1, part);
  mm1_comb_k<<<512, 256, 0, stream>>>(part, b1, t1);
  hg_tail_k<<<8, 512, 0, stream>>>(G, t1, w2, b2, f2, outv);
  head_k<<<32, 256, 0, stream>>>(outv, hw, hb, f2, out);
}

// Round 4
// 536.281 us; speedup vs baseline: 3.2377x; 1.0720x over previous
//
#include <hip/hip_runtime.h>
#include <hip/hip_bf16.h>

#define RFL(x) __builtin_amdgcn_readfirstlane(x)

// ---------------- conv1: [8,3,448,448] (chan-reversed) -> [8,64,150,150], 5x5 s3 p2, ReLU
__global__ void __launch_bounds__(256) conv1_k(const float* __restrict__ x,
                                               const float* __restrict__ w,
                                               const float* __restrict__ bias,
                                               float* __restrict__ out) {
  __shared__ float xt[3][5][456];   // col = ix+2
  int b = blockIdx.x / 150;
  int py = blockIdx.x % 150;
  int t = threadIdx.x;
  int iy0 = py * 3 - 2;
  for (int e = t; e < 6840; e += 256) {
    int c = e / 2280;
    int rest = e % 2280;
    int r = rest / 456;
    int col = rest % 456;
    int iy = iy0 + r;
    int ix = col - 2;
    float v = 0.f;
    if (iy >= 0 && iy < 448 && ix >= 0 && ix < 448)
      v = x[((size_t)(b * 3 + (2 - c)) * 448 + iy) * 448 + ix];
    xt[c][r][col] = v;
  }
  __syncthreads();
  int lane = t & 63;
  int ob = RFL(t >> 6) * 16;
  for (int sub = 0; sub < 3; ++sub) {
    int px = sub * 64 + lane;
    float acc[16];
#pragma unroll
    for (int u = 0; u < 16; ++u) acc[u] = bias[ob + u];
#pragma unroll
    for (int c = 0; c < 3; ++c)
#pragma unroll
      for (int ky = 0; ky < 5; ++ky)
#pragma unroll
        for (int kx = 0; kx < 5; ++kx) {
          float xv = xt[c][ky][px * 3 + kx];
#pragma unroll
          for (int u = 0; u < 16; ++u)
            acc[u] += xv * w[(ob + u) * 75 + c * 25 + ky * 5 + kx];  // s_load
        }
    if (px < 150) {
#pragma unroll
      for (int u = 0; u < 16; ++u)
        out[(size_t)(b * 64 + ob + u) * 22500 + py * 150 + px] = fmaxf(acc[u], 0.f);
    }
  }
}

// ---------------- conv2 split-K partial: block = (b,py,ch of 8 input chans)
__global__ void __launch_bounds__(256) conv2p_k(const float* __restrict__ h1,
                                                const float* __restrict__ w,
                                                float* __restrict__ part2) {
  __shared__ float ht[8][5][152];
  int blk = blockIdx.x;
  int ch = blk & 7;
  int bpy = blk >> 3;
  int b = bpy / 50;
  int py = bpy % 50;
  int t = threadIdx.x;
  int iy0 = py * 3 - 2;
  for (int e = t; e < 6080; e += 256) {
    int c = e / 760;
    int rest = e % 760;
    int r = rest / 152;
    int col = rest % 152;
    int iy = iy0 + r;
    int ix = col - 2;
    float v = 0.f;
    if (iy >= 0 && iy < 150 && ix >= 0 && ix < 150)
      v = h1[((size_t)(b * 64 + ch * 8 + c) * 150 + iy) * 150 + ix];
    ht[c][r][col] = v;
  }
  __syncthreads();
  int lane = t & 63;
  int ob = RFL(t >> 6) * 8;
  int px = lane;
  float acc[8];
#pragma unroll
  for (int u = 0; u < 8; ++u) acc[u] = 0.f;
#pragma unroll
  for (int c = 0; c < 8; ++c)
#pragma unroll
    for (int ky = 0; ky < 5; ++ky)
#pragma unroll
      for (int kx = 0; kx < 5; ++kx) {
        float xv = ht[c][ky][px * 3 + kx];
#pragma unroll
        for (int u = 0; u < 8; ++u)
          acc[u] += xv * w[(ob + u) * 1600 + (ch * 8 + c) * 25 + ky * 5 + kx];  // s_load
      }
  if (px < 50) {
#pragma unroll
    for (int u = 0; u < 8; ++u)
      part2[((size_t)ch * 256 + b * 32 + ob + u) * 2500 + py * 50 + px] = acc[u];
  }
}

// ---------------- conv2 combine: sum 8 partials + bias + relu -> ft and ftT
__global__ void __launch_bounds__(256) comb2_k(const float* __restrict__ part2,
                                               const float* __restrict__ bias,
                                               float* __restrict__ ft,
                                               float* __restrict__ ftT) {
  __shared__ float tile[32][51];
  int b = blockIdx.x / 50;
  int py = blockIdx.x % 50;
  int t = threadIdx.x;
  for (int e = t; e < 1600; e += 256) {
    int o = e / 50, p = e % 50;
    float s = bias[o];
#pragma unroll
    for (int ch = 0; ch < 8; ++ch)
      s += part2[((size_t)ch * 256 + b * 32 + o) * 2500 + py * 50 + p];
    tile[o][p] = fmaxf(s, 0.f);
  }
  __syncthreads();
  for (int e = t; e < 1600; e += 256) {
    int o = e / 50, p = e % 50;
    ft[(size_t)(b * 32 + o) * 2500 + py * 50 + p] = tile[o][p];
  }
  for (int e = t; e < 1600; e += 256) {
    int p = e >> 5, o = e & 31;
    ftT[((size_t)b * 2500 + py * 50 + p) * 32 + o] = tile[o][p];
  }
}

// ---------------- conv2 fallback (monolithic, 51.3MB ws) — used if ws too small
__global__ void __launch_bounds__(256) conv2_fb_k(const float* __restrict__ h1,
                                                  const float* __restrict__ w,
                                                  const float* __restrict__ bias,
                                                  float* __restrict__ ft,
                                                  float* __restrict__ ftT) {
  __shared__ float ht[16][5][152];
  __shared__ float tile[32][51];
  int b = blockIdx.x / 50;
  int py = blockIdx.x % 50;
  int t = threadIdx.x;
  int lane = t & 63;
  int ob = RFL(t >> 6) * 8;
  int px = lane;
  int iy0 = py * 3 - 2;
  float acc[8];
#pragma unroll
  for (int u = 0; u < 8; ++u) acc[u] = 0.f;
  for (int ch = 0; ch < 4; ++ch) {
    __syncthreads();
    for (int e = t; e < 12160; e += 256) {
      int c = e / 760;
      int rest = e % 760;
      int r = rest / 152;
      int col = rest % 152;
      int iy = iy0 + r;
      int ix = col - 2;
      float v = 0.f;
      if (iy >= 0 && iy < 150 && ix >= 0 && ix < 150)
        v = h1[((size_t)(b * 64 + ch * 16 + c) * 150 + iy) * 150 + ix];
      ht[c][r][col] = v;
    }
    __syncthreads();
    for (int c = 0; c < 16; ++c) {
#pragma unroll
      for (int ky = 0; ky < 5; ++ky)
#pragma unroll
        for (int kx = 0; kx < 5; ++kx) {
          float xv = ht[c][ky][px * 3 + kx];
#pragma unroll
          for (int u = 0; u < 8; ++u)
            acc[u] += xv * w[(ob + u) * 1600 + (ch * 16 + c) * 25 + ky * 5 + kx];
        }
    }
  }
  if (px < 50) {
#pragma unroll
    for (int u = 0; u < 8; ++u)
      tile[ob + u][px] = fmaxf(acc[u] + bias[ob + u], 0.f);
  }
  __syncthreads();
  for (int e = t; e < 1600; e += 256) {
    int o = e / 50, p = e % 50;
    ft[(size_t)(b * 32 + o) * 2500 + py * 50 + p] = tile[o][p];
  }
  for (int e = t; e < 1600; e += 256) {
    int p = e >> 5, o = e & 31;
    ftT[((size_t)b * 2500 + py * 50 + p) * 32 + o] = tile[o][p];
  }
}

// ---------------- feature branch
__global__ void __launch_bounds__(512) fk_encqkv(const float* __restrict__ xf,
                                                 const float* __restrict__ ew, const float* __restrict__ eb,
                                                 const float* __restrict__ wq, const float* __restrict__ bq,
                                                 const float* __restrict__ wk, const float* __restrict__ bk,
                                                 const float* __restrict__ wv, const float* __restrict__ bv,
                                                 float* __restrict__ qkv) {
  __shared__ float fs[512];
  int b = blockIdx.x, j = threadIdx.x;
  float acc = eb[j];
  for (int c = 0; c < 36; ++c) acc += xf[b * 36 + c] * ew[c * 512 + j];
  fs[j] = fmaxf(acc, 0.f);
  __syncthreads();
  float aq = bq[j], ak = bk[j], av = bv[j];
  for (int c = 0; c < 512; ++c) {
    float fv = fs[c];
    aq += fv * wq[c * 512 + j];
    ak += fv * wk[c * 512 + j];
    av += fv * wv[c * 512 + j];
  }
  qkv[b * 512 + j] = aq;
  qkv[4096 + b * 512 + j] = ak;
  qkv[8192 + b * 512 + j] = av;
}

__global__ void __launch_bounds__(256) fk_attn(const float* __restrict__ qkv,
                                               float* __restrict__ ao) {
  __shared__ float att[2][8][8];
  int t = threadIdx.x;
  const float* q = qkv;
  const float* kk = qkv + 4096;
  const float* v = qkv + 8192;
  if (t < 128) {
    int h = t >> 6, b = (t >> 3) & 7, c = t & 7;
    float acc = 0.f;
    for (int d = 0; d < 256; ++d)
      acc += q[b * 512 + h * 256 + d] * kk[c * 512 + h * 256 + d];
    att[h][b][c] = acc * (1.f / 16.f);
  }
  __syncthreads();
  if (t < 16) {
    int h = t >> 3, b = t & 7;
    float mx = -1e30f;
    for (int c = 0; c < 8; ++c) mx = fmaxf(mx, att[h][b][c]);
    float e[8], s = 0.f;
    for (int c = 0; c < 8; ++c) { e[c] = expf(att[h][b][c] - mx); s += e[c]; }
    for (int c = 0; c < 8; ++c) att[h][b][c] = e[c] / s;
  }
  __syncthreads();
  for (int i = t; i < 4096; i += 256) {
    int b = i >> 9, j = i & 511, h = j >> 8;
    float acc = 0.f;
#pragma unroll
    for (int c = 0; c < 8; ++c) acc += att[h][b][c] * v[c * 512 + j];
    ao[b * 512 + j] = acc;
  }
}

__global__ void __launch_bounds__(512) fk_odec(const float* __restrict__ ao,
                                               const float* __restrict__ wo, const float* __restrict__ bo,
                                               const float* __restrict__ dw, const float* __restrict__ db,
                                               float* __restrict__ f2) {
  __shared__ float os[512];
  int b = blockIdx.x, j = threadIdx.x;
  float acc = bo[j];
  for (int c = 0; c < 512; ++c) acc += ao[b * 512 + c] * wo[(size_t)c * 512 + j];
  os[j] = acc;
  __syncthreads();
  if (j < 32) {
    float a2 = db[j];
    for (int c = 0; c < 512; ++c) a2 += os[c] * dw[c * 32 + j];
    f2[b * 32 + j] = fmaxf(a2, 0.f);
  }
}

// ---------------- hypergraph G per sample
__global__ void __launch_bounds__(256) hg_G_k(const float* __restrict__ ftT,
                                              float* __restrict__ Gout) {
  int b = blockIdx.x;
  const float* S = ftT + (size_t)b * 80000;  // [2500][32]
  __shared__ float gram[32][32];
  __shared__ float d[32][32];
  __shared__ float avg[32];
  __shared__ float Hm[32][32];
  __shared__ float Hn[32][32];
  __shared__ float DE[32];
  __shared__ float dvi[32];
  int t = threadIdx.x;
  {
    int i = t >> 3;
    int j0 = (t & 7) * 4;
    float4 acc[4];
#pragma unroll
    for (int q = 0; q < 4; ++q) acc[q] = make_float4(0.f, 0.f, 0.f, 0.f);
    for (int p = 0; p < 625; ++p) {
#pragma unroll
      for (int q = 0; q < 4; ++q) {
        int pp = p + q * 625;
        float ai = S[pp * 32 + i];
        const float4 bj = *(const float4*)(S + pp * 32 + j0);
        acc[q].x += ai * bj.x; acc[q].y += ai * bj.y;
        acc[q].z += ai * bj.z; acc[q].w += ai * bj.w;
      }
    }
    gram[i][j0]     = (acc[0].x + acc[1].x) + (acc[2].x + acc[3].x);
    gram[i][j0 + 1] = (acc[0].y + acc[1].y) + (acc[2].y + acc[3].y);
    gram[i][j0 + 2] = (acc[0].z + acc[1].z) + (acc[2].z + acc[3].z);
    gram[i][j0 + 3] = (acc[0].w + acc[1].w) + (acc[2].w + acc[3].w);
  }
  __syncthreads();
  for (int e = t; e < 1024; e += 256) {
    int i = e >> 5, j = e & 31;
    float d2 = gram[i][i] + gram[j][j] - 2.f * gram[i][j];
    float dd = sqrtf(fmaxf(d2, 0.f));
    if (i == j) dd = 0.f;
    d[i][j] = dd;
  }
  __syncthreads();
  if (t < 32) {
    float s = 0.f;
    for (int j = 0; j < 32; ++j) s += d[t][j];
    avg[t] = s * (1.f / 32.f);
  }
  for (int e = t; e < 1024; e += 256) Hm[e >> 5][e & 31] = 0.f;
  __syncthreads();
  if (t < 32) {
    unsigned picked = 0;
    float a = avg[t];
    float inv = 1.f / (a * a);
    for (int s = 0; s < 5; ++s) {
      float best = 1e30f;
      int bi = 0;
      for (int j = 0; j < 32; ++j) {
        if (picked & (1u << j)) continue;
        float dv = d[t][j];
        if (dv < best) { best = dv; bi = j; }
      }
      picked |= 1u << bi;
      Hm[bi][t] = expf(-best * best * inv);
    }
  }
  __syncthreads();
  if (t < 32) {
    float se = 0.f, sv = 0.f;
    for (int r = 0; r < 32; ++r) se += Hm[r][t];
    for (int c = 0; c < 32; ++c) sv += Hm[t][c];
    DE[t] = se;
    dvi[t] = 1.f / sqrtf(sv);
  }
  __syncthreads();
  for (int e = t; e < 1024; e += 256) {
    int i = e >> 5, j = e & 31;
    Hn[i][j] = Hm[i][j] * (1.f / DE[j]);
  }
  __syncthreads();
  for (int e = t; e < 1024; e += 256) {
    int i = e >> 5, j = e & 31;
    float acc = 0.f;
#pragma unroll
    for (int c = 0; c < 32; ++c) acc += Hn[i][c] * Hm[j][c];
    Gout[(size_t)b * 1024 + e] = dvi[i] * acc * dvi[j];
  }
}

// ---------------- t1 partials: ft[256,2500] @ w1[2500,512], 16 rowgroups x 16 k-chunks
__global__ void __launch_bounds__(512) hg_mm1_k(const float* __restrict__ ft,
                                                const float* __restrict__ w1,
                                                float* __restrict__ part) {
  int rg = blockIdx.x;
  int ch = blockIdx.y;
  int j = threadIdx.x;
  int r0 = rg * 16;
  int c0 = ch * 156 + min(ch, 4);
  int cn = 156 + (ch < 4 ? 1 : 0);
  float acc[16];
#pragma unroll
  for (int r = 0; r < 16; ++r) acc[r] = 0.f;
#pragma unroll 4
  for (int c = c0; c < c0 + cn; ++c) {
    float wv = w1[(size_t)c * 512 + j];
#pragma unroll
    for (int r = 0; r < 16; ++r)
      acc[r] += ft[(size_t)(r0 + r) * 2500 + c] * wv;  // uniform -> s_load
  }
#pragma unroll
  for (int r = 0; r < 16; ++r)
    part[(size_t)ch * 131072 + (r0 + r) * 512 + j] = acc[r];
}

__global__ void __launch_bounds__(256) mm1_comb_k(const float* __restrict__ part,
                                                  const float* __restrict__ b1,
                                                  float* __restrict__ t1) {
  int idx = blockIdx.x * 256 + threadIdx.x;
  if (idx >= 131072) return;
  float s = b1[idx & 511];
#pragma unroll
  for (int ch = 0; ch < 16; ++ch) s += part[(size_t)ch * 131072 + idx];
  t1[idx] = s;
}

// ---------------- per-sample tail
__global__ void __launch_bounds__(512) hg_tail_k(const float* __restrict__ G,
                                                 const float* __restrict__ t1,
                                                 const float* __restrict__ w2,
                                                 const float* __restrict__ b2,
                                                 const float* __restrict__ f2,
                                                 float* __restrict__ outv) {
  int b = blockIdx.x;
  __shared__ float zs[32][512];
  __shared__ float t2s[32][32];
  int t = threadIdx.x;
  const float* Gb = G + b * 1024;
  const float* t1b = t1 + b * 16384;
  {
    int j = t;
    float acc[32];
#pragma unroll
    for (int i = 0; i < 32; ++i) acc[i] = 0.f;
    for (int c = 0; c < 32; ++c) {
      float tv = t1b[c * 512 + j];
#pragma unroll
      for (int i = 0; i < 32; ++i) acc[i] += Gb[i * 32 + c] * tv;
    }
#pragma unroll
    for (int i = 0; i < 32; ++i) zs[i][j] = fmaxf(acc[i], 0.f);
  }
  __syncthreads();
#pragma unroll
  for (int e2 = 0; e2 < 2; ++e2) {
    int e = t + e2 * 512;
    int i = e >> 5, jj = e & 31;
    float acc = b2[jj];
    for (int c = 0; c < 512; ++c) acc += zs[i][c] * w2[c * 32 + jj];
    t2s[i][jj] = acc;
  }
  __syncthreads();
  if (t < 32) {
    int j = t;
    float s = 0.f;
    for (int i = 0; i < 32; ++i) {
      float acc = 0.f;
#pragma unroll
      for (int c = 0; c < 32; ++c) acc += Gb[i * 32 + c] * t2s[c][j];
      s += acc;
    }
    outv[b * 32 + j] = s * (1.f / 32.f) + f2[b * 32 + j];
  }
}

// ---------------- head
__global__ void __launch_bounds__(256) head_k(const float* __restrict__ outv,
                                              const float* __restrict__ hw,
                                              const float* __restrict__ hb,
                                              const float* __restrict__ f2,
                                              float* __restrict__ dout) {
  int i = blockIdx.x * 256 + threadIdx.x;
  if (i < 8000) {
    int b = i / 1000, j = i % 1000;
    float acc = hb[j];
#pragma unroll
    for (int c = 0; c < 32; ++c) acc += outv[b * 32 + c] * hw[c * 1000 + j];
    dout[i] = acc;
  }
  if (i < 256) dout[8000 + i] = f2[i];
}

extern "C" void kernel_launch(void* const* d_in, const int* in_sizes, int n_in,
                              void* d_out, int out_size, void* d_ws, size_t ws_size,
                              hipStream_t stream) {
  const float* x     = (const float*)d_in[0];
  const float* xf    = (const float*)d_in[1];
  const float* c1w   = (const float*)d_in[2];
  const float* c1b   = (const float*)d_in[3];
  const float* c2w   = (const float*)d_in[4];
  const float* c2b   = (const float*)d_in[5];
  const float* enc_w = (const float*)d_in[6];
  const float* enc_b = (const float*)d_in[7];
  const float* wq    = (const float*)d_in[8];
  const float* bq    = (const float*)d_in[9];
  const float* wk    = (const float*)d_in[10];
  const float* bk    = (const float*)d_in[11];
  const float* wv    = (const float*)d_in[12];
  const float* bv    = (const float*)d_in[13];
  const float* wo    = (const float*)d_in[14];
  const float* bo    = (const float*)d_in[15];
  const float* dec_w = (const float*)d_in[16];
  const float* dec_b = (const float*)d_in[17];
  const float* w1    = (const float*)d_in[18];
  const float* b1    = (const float*)d_in[19];
  const float* w2    = (const float*)d_in[20];
  const float* b2    = (const float*)d_in[21];
  const float* hw    = (const float*)d_in[22];
  const float* hb    = (const float*)d_in[23];
  float* out = (float*)d_out;

  float* ws = (float*)d_ws;
  // layout (floats):
  float* h1   = ws;                  // [0, 11,520,000)  dead after conv2 partials
  float* ftb  = ws + 11520000;       // 640,000
  float* ftT  = ws + 12160000;       // 640,000
  float* qkv  = ws + 12800000;       // 12,288
  float* ao   = ws + 12812288;       // 4,096
  float* f2   = ws + 12816384;       // 256
  float* outv = ws + 12816640;       // 256
  float* G    = ws + 12816896;       // 8,192  -> 12,825,088
  float* part2= ws + 12825088;       // 5,120,000 -> 17,945,088 (71.8 MB)
  // overlays on dead h1 region (used only after conv2):
  float* part = ws;                  // 2,097,152
  float* t1   = ws + 2097152;        // 131,072

  bool big = ws_size >= (size_t)17945088 * 4;

  conv1_k<<<8 * 150, 256, 0, stream>>>(x, c1w, c1b, h1);
  if (big) {
    conv2p_k<<<8 * 50 * 8, 256, 0, stream>>>(h1, c2w, part2);
    comb2_k<<<8 * 50, 256, 0, stream>>>(part2, c2b, ftb, ftT);
  } else {
    conv2_fb_k<<<8 * 50, 256, 0, stream>>>(h1, c2w, c2b, ftb, ftT);
  }

  fk_encqkv<<<8, 512, 0, stream>>>(xf, enc_w, enc_b, wq, bq, wk, bk, wv, bv, qkv);
  fk_attn<<<1, 256, 0, stream>>>(qkv, ao);
  fk_odec<<<8, 512, 0, stream>>>(ao, wo, bo, dec_w, dec_b, f2);

  hg_G_k<<<8, 256, 0, stream>>>(ftT, G);
  dim3 gm(16, 16);
  hg_mm1_k<<<gm, 512, 0, stream>>>(ftb, w1, part);
  mm1_comb_k<<<512, 256, 0, stream>>>(part, b1, t1);
  hg_tail_k<<<8, 512, 0, stream>>>(G, t1, w2, b2, f2, outv);
  head_k<<<32, 256, 0, stream>>>(outv, hw, hb, f2, out);
}

// Round 5
// 322.426 us; speedup vs baseline: 5.3852x; 1.6633x over previous
//
#include <hip/hip_runtime.h>
#include <hip/hip_bf16.h>

#define RFL(x) __builtin_amdgcn_readfirstlane(x)

// ---------------- weight transpose: c1wT[k][64], c2wT[k][32]
__global__ void __launch_bounds__(256) wT_k(const float* __restrict__ c1w,
                                            const float* __restrict__ c2w,
                                            float* __restrict__ c1wT,
                                            float* __restrict__ c2wT) {
  int idx = blockIdx.x * 256 + threadIdx.x;
  if (idx < 4800) {
    int o = idx / 75, k = idx % 75;
    c1wT[k * 64 + o] = c1w[idx];
  } else if (idx < 56000) {
    int j = idx - 4800;
    int o = j / 1600, k = j % 1600;
    c2wT[k * 32 + o] = c2w[j];
  }
}

// ---------------- conv1: [8,3,448,448] (chan-reversed) -> [8,64,150,150], 5x5 s3 p2, ReLU
__global__ void __launch_bounds__(256) conv1_k(const float* __restrict__ x,
                                               const float* __restrict__ wT,
                                               const float* __restrict__ bias,
                                               float* __restrict__ out) {
  __shared__ float xt[3][5][456];   // col = ix+2
  int b = blockIdx.x / 150;
  int py = blockIdx.x % 150;
  int t = threadIdx.x;
  int iy0 = py * 3 - 2;
  for (int e = t; e < 6840; e += 256) {
    int c = e / 2280;
    int rest = e % 2280;
    int r = rest / 456;
    int col = rest % 456;
    int iy = iy0 + r;
    int ix = col - 2;
    float v = 0.f;
    if (iy >= 0 && iy < 448 && ix >= 0 && ix < 448)
      v = x[((size_t)(b * 3 + (2 - c)) * 448 + iy) * 448 + ix];
    xt[c][r][col] = v;
  }
  __syncthreads();
  int lane = t & 63;
  int ob = RFL(t >> 6) * 16;
  for (int sub = 0; sub < 3; ++sub) {
    int px = sub * 64 + lane;
    int pxc = min(px, 149);
    float acc[16];
#pragma unroll
    for (int u = 0; u < 16; ++u) acc[u] = 0.f;
#pragma unroll
    for (int c = 0; c < 3; ++c)
#pragma unroll
      for (int ky = 0; ky < 5; ++ky)
#pragma unroll
        for (int kx = 0; kx < 5; ++kx) {
          float xv = xt[c][ky][pxc * 3 + kx];
          const float* wr = wT + (c * 25 + ky * 5 + kx) * 64 + ob;  // uniform -> s_load_dwordx16
#pragma unroll
          for (int u = 0; u < 16; ++u) acc[u] += xv * wr[u];
        }
    if (px < 150) {
#pragma unroll
      for (int u = 0; u < 16; ++u)
        out[(size_t)(b * 64 + ob + u) * 22500 + py * 150 + px] =
            fmaxf(acc[u] + bias[ob + u], 0.f);
    }
  }
}

// ---------------- conv2 split-K partial: block = (b,py,ch of 8 input chans)
__global__ void __launch_bounds__(256) conv2p_k(const float* __restrict__ h1,
                                                const float* __restrict__ wT,
                                                float* __restrict__ part2) {
  __shared__ float ht[8][5][152];
  int blk = blockIdx.x;
  int ch = blk & 7;
  int bpy = blk >> 3;
  int b = bpy / 50;
  int py = bpy % 50;
  int t = threadIdx.x;
  int iy0 = py * 3 - 2;
  for (int e = t; e < 6080; e += 256) {
    int c = e / 760;
    int rest = e % 760;
    int r = rest / 152;
    int col = rest % 152;
    int iy = iy0 + r;
    int ix = col - 2;
    float v = 0.f;
    if (iy >= 0 && iy < 150 && ix >= 0 && ix < 150)
      v = h1[((size_t)(b * 64 + ch * 8 + c) * 150 + iy) * 150 + ix];
    ht[c][r][col] = v;
  }
  __syncthreads();
  int lane = t & 63;
  int ob = RFL(t >> 6) * 8;
  int px = lane;
  int pxc = min(px, 49);
  float acc[8];
#pragma unroll
  for (int u = 0; u < 8; ++u) acc[u] = 0.f;
#pragma unroll
  for (int c = 0; c < 8; ++c)
#pragma unroll
    for (int ky = 0; ky < 5; ++ky)
#pragma unroll
      for (int kx = 0; kx < 5; ++kx) {
        float xv = ht[c][ky][pxc * 3 + kx];
        const float* wr = wT + ((ch * 8 + c) * 25 + ky * 5 + kx) * 32 + ob;  // s_load_dwordx8
#pragma unroll
        for (int u = 0; u < 8; ++u) acc[u] += xv * wr[u];
      }
  if (px < 50) {
#pragma unroll
    for (int u = 0; u < 8; ++u)
      part2[((size_t)ch * 256 + b * 32 + ob + u) * 2500 + py * 50 + px] = acc[u];
  }
}

// ---------------- conv2 combine: sum 8 partials + bias + relu -> ft and ftT
__global__ void __launch_bounds__(256) comb2_k(const float* __restrict__ part2,
                                               const float* __restrict__ bias,
                                               float* __restrict__ ft,
                                               float* __restrict__ ftT) {
  __shared__ float tile[32][51];
  int b = blockIdx.x / 50;
  int py = blockIdx.x % 50;
  int t = threadIdx.x;
  for (int e = t; e < 1600; e += 256) {
    int o = e / 50, p = e % 50;
    float s = bias[o];
#pragma unroll
    for (int ch = 0; ch < 8; ++ch)
      s += part2[((size_t)ch * 256 + b * 32 + o) * 2500 + py * 50 + p];
    tile[o][p] = fmaxf(s, 0.f);
  }
  __syncthreads();
  for (int e = t; e < 1600; e += 256) {
    int o = e / 50, p = e % 50;
    ft[(size_t)(b * 32 + o) * 2500 + py * 50 + p] = tile[o][p];
  }
  for (int e = t; e < 1600; e += 256) {
    int p = e >> 5, o = e & 31;
    ftT[((size_t)b * 2500 + py * 50 + p) * 32 + o] = tile[o][p];
  }
}

// ---------------- conv2 fallback (monolithic) — used if ws too small
__global__ void __launch_bounds__(256) conv2_fb_k(const float* __restrict__ h1,
                                                  const float* __restrict__ w,
                                                  const float* __restrict__ bias,
                                                  float* __restrict__ ft,
                                                  float* __restrict__ ftT) {
  __shared__ float ht[16][5][152];
  __shared__ float tile[32][51];
  int b = blockIdx.x / 50;
  int py = blockIdx.x % 50;
  int t = threadIdx.x;
  int lane = t & 63;
  int ob = RFL(t >> 6) * 8;
  int px = lane;
  int pxc = min(px, 49);
  int iy0 = py * 3 - 2;
  float acc[8];
#pragma unroll
  for (int u = 0; u < 8; ++u) acc[u] = 0.f;
  for (int ch = 0; ch < 4; ++ch) {
    __syncthreads();
    for (int e = t; e < 12160; e += 256) {
      int c = e / 760;
      int rest = e % 760;
      int r = rest / 152;
      int col = rest % 152;
      int iy = iy0 + r;
      int ix = col - 2;
      float v = 0.f;
      if (iy >= 0 && iy < 150 && ix >= 0 && ix < 150)
        v = h1[((size_t)(b * 64 + ch * 16 + c) * 150 + iy) * 150 + ix];
      ht[c][r][col] = v;
    }
    __syncthreads();
    for (int c = 0; c < 16; ++c) {
#pragma unroll
      for (int ky = 0; ky < 5; ++ky)
#pragma unroll
        for (int kx = 0; kx < 5; ++kx) {
          float xv = ht[c][ky][pxc * 3 + kx];
#pragma unroll
          for (int u = 0; u < 8; ++u)
            acc[u] += xv * w[(ob + u) * 1600 + (ch * 16 + c) * 25 + ky * 5 + kx];
        }
    }
  }
  if (px < 50) {
#pragma unroll
    for (int u = 0; u < 8; ++u)
      tile[ob + u][px] = fmaxf(acc[u] + bias[ob + u], 0.f);
  }
  __syncthreads();
  for (int e = t; e < 1600; e += 256) {
    int o = e / 50, p = e % 50;
    ft[(size_t)(b * 32 + o) * 2500 + py * 50 + p] = tile[o][p];
  }
  for (int e = t; e < 1600; e += 256) {
    int p = e >> 5, o = e & 31;
    ftT[((size_t)b * 2500 + py * 50 + p) * 32 + o] = tile[o][p];
  }
}

// ---------------- feature branch
__global__ void __launch_bounds__(512) fk_encqkv(const float* __restrict__ xf,
                                                 const float* __restrict__ ew, const float* __restrict__ eb,
                                                 const float* __restrict__ wq, const float* __restrict__ bq,
                                                 const float* __restrict__ wk, const float* __restrict__ bk,
                                                 const float* __restrict__ wv, const float* __restrict__ bv,
                                                 float* __restrict__ qkv) {
  __shared__ float fs[512];
  int b = blockIdx.x, j = threadIdx.x;
  float acc = eb[j];
  for (int c = 0; c < 36; ++c) acc += xf[b * 36 + c] * ew[c * 512 + j];
  fs[j] = fmaxf(acc, 0.f);
  __syncthreads();
  float aq = bq[j], ak = bk[j], av = bv[j];
  for (int c = 0; c < 512; ++c) {
    float fv = fs[c];
    aq += fv * wq[c * 512 + j];
    ak += fv * wk[c * 512 + j];
    av += fv * wv[c * 512 + j];
  }
  qkv[b * 512 + j] = aq;
  qkv[4096 + b * 512 + j] = ak;
  qkv[8192 + b * 512 + j] = av;
}

__global__ void __launch_bounds__(256) fk_attn(const float* __restrict__ qkv,
                                               float* __restrict__ ao) {
  __shared__ float att[2][8][8];
  int t = threadIdx.x;
  const float* q = qkv;
  const float* kk = qkv + 4096;
  const float* v = qkv + 8192;
  if (t < 128) {
    int h = t >> 6, b = (t >> 3) & 7, c = t & 7;
    float acc = 0.f;
    for (int d = 0; d < 256; ++d)
      acc += q[b * 512 + h * 256 + d] * kk[c * 512 + h * 256 + d];
    att[h][b][c] = acc * (1.f / 16.f);
  }
  __syncthreads();
  if (t < 16) {
    int h = t >> 3, b = t & 7;
    float mx = -1e30f;
    for (int c = 0; c < 8; ++c) mx = fmaxf(mx, att[h][b][c]);
    float e[8], s = 0.f;
    for (int c = 0; c < 8; ++c) { e[c] = expf(att[h][b][c] - mx); s += e[c]; }
    for (int c = 0; c < 8; ++c) att[h][b][c] = e[c] / s;
  }
  __syncthreads();
  for (int i = t; i < 4096; i += 256) {
    int b = i >> 9, j = i & 511, h = j >> 8;
    float acc = 0.f;
#pragma unroll
    for (int c = 0; c < 8; ++c) acc += att[h][b][c] * v[c * 512 + j];
    ao[b * 512 + j] = acc;
  }
}

__global__ void __launch_bounds__(512) fk_odec(const float* __restrict__ ao,
                                               const float* __restrict__ wo, const float* __restrict__ bo,
                                               const float* __restrict__ dw, const float* __restrict__ db,
                                               float* __restrict__ f2) {
  __shared__ float os[512];
  int b = blockIdx.x, j = threadIdx.x;
  float acc = bo[j];
  for (int c = 0; c < 512; ++c) acc += ao[b * 512 + c] * wo[(size_t)c * 512 + j];
  os[j] = acc;
  __syncthreads();
  if (j < 32) {
    float a2 = db[j];
    for (int c = 0; c < 512; ++c) a2 += os[c] * dw[c * 32 + j];
    f2[b * 32 + j] = fmaxf(a2, 0.f);
  }
}

// ---------------- gram partials: grid (8,25), each block does 100 p-rows
__global__ void __launch_bounds__(256) hg_gram_k(const float* __restrict__ ftT,
                                                 float* __restrict__ gramP) {
  __shared__ float sl[100][32];
  int b = blockIdx.x, ch = blockIdx.y;
  const float* S = ftT + (size_t)b * 80000 + ch * 3200;
  int t = threadIdx.x;
  for (int e = t; e < 800; e += 256)
    ((float4*)sl)[e] = ((const float4*)S)[e];
  __syncthreads();
  int i = t >> 3, j0 = (t & 7) * 4;
  float4 a0 = make_float4(0.f, 0.f, 0.f, 0.f);
  float4 a1 = make_float4(0.f, 0.f, 0.f, 0.f);
  for (int p = 0; p < 100; p += 2) {
    float ai0 = sl[p][i];
    float4 b0 = *(const float4*)&sl[p][j0];
    a0.x += ai0 * b0.x; a0.y += ai0 * b0.y; a0.z += ai0 * b0.z; a0.w += ai0 * b0.w;
    float ai1 = sl[p + 1][i];
    float4 b1 = *(const float4*)&sl[p + 1][j0];
    a1.x += ai1 * b1.x; a1.y += ai1 * b1.y; a1.z += ai1 * b1.z; a1.w += ai1 * b1.w;
  }
  float4 r = make_float4(a0.x + a1.x, a0.y + a1.y, a0.z + a1.z, a0.w + a1.w);
  *(float4*)(gramP + ((size_t)(b * 25 + ch)) * 1024 + t * 4) = r;
}

// ---------------- G combine: sum partials, distances, top-5, normalize
__global__ void __launch_bounds__(256) hg_G2_k(const float* __restrict__ gramP,
                                               float* __restrict__ Gout) {
  int b = blockIdx.x;
  __shared__ float gram[32][32];
  __shared__ float d[32][32];
  __shared__ float avg[32];
  __shared__ float Hm[32][32];
  __shared__ float Hn[32][32];
  __shared__ float DE[32];
  __shared__ float dvi[32];
  int t = threadIdx.x;
  {
    float4 s = make_float4(0.f, 0.f, 0.f, 0.f);
    for (int ch = 0; ch < 25; ++ch) {
      float4 v = *(const float4*)(gramP + ((size_t)(b * 25 + ch)) * 1024 + t * 4);
      s.x += v.x; s.y += v.y; s.z += v.z; s.w += v.w;
    }
    *(float4*)(&gram[0][0] + t * 4) = s;
  }
  __syncthreads();
  for (int e = t; e < 1024; e += 256) {
    int i = e >> 5, j = e & 31;
    float d2 = gram[i][i] + gram[j][j] - 2.f * gram[i][j];
    float dd = sqrtf(fmaxf(d2, 0.f));
    if (i == j) dd = 0.f;
    d[i][j] = dd;
  }
  __syncthreads();
  if (t < 32) {
    float s = 0.f;
    for (int j = 0; j < 32; ++j) s += d[t][j];
    avg[t] = s * (1.f / 32.f);
  }
  for (int e = t; e < 1024; e += 256) Hm[e >> 5][e & 31] = 0.f;
  __syncthreads();
  if (t < 32) {
    unsigned picked = 0;
    float a = avg[t];
    float inv = 1.f / (a * a);
    for (int s = 0; s < 5; ++s) {
      float best = 1e30f;
      int bi = 0;
      for (int j = 0; j < 32; ++j) {
        if (picked & (1u << j)) continue;
        float dv = d[t][j];
        if (dv < best) { best = dv; bi = j; }
      }
      picked |= 1u << bi;
      Hm[bi][t] = expf(-best * best * inv);
    }
  }
  __syncthreads();
  if (t < 32) {
    float se = 0.f, sv = 0.f;
    for (int r = 0; r < 32; ++r) se += Hm[r][t];
    for (int c = 0; c < 32; ++c) sv += Hm[t][c];
    DE[t] = se;
    dvi[t] = 1.f / sqrtf(sv);
  }
  __syncthreads();
  for (int e = t; e < 1024; e += 256) {
    int i = e >> 5, j = e & 31;
    Hn[i][j] = Hm[i][j] * (1.f / DE[j]);
  }
  __syncthreads();
  for (int e = t; e < 1024; e += 256) {
    int i = e >> 5, j = e & 31;
    float acc = 0.f;
#pragma unroll
    for (int c = 0; c < 32; ++c) acc += Hn[i][c] * Hm[j][c];
    Gout[(size_t)b * 1024 + e] = dvi[i] * acc * dvi[j];
  }
}

// ---------------- t1 partials: ft[256,2500] @ w1[2500,512]
__global__ void __launch_bounds__(512) hg_mm1_k(const float* __restrict__ ft,
                                                const float* __restrict__ w1,
                                                float* __restrict__ part) {
  int rg = blockIdx.x;
  int ch = blockIdx.y;
  int j = threadIdx.x;
  int r0 = rg * 16;
  int c0 = ch * 156 + min(ch, 4);
  int cn = 156 + (ch < 4 ? 1 : 0);
  float acc[16];
#pragma unroll
  for (int r = 0; r < 16; ++r) acc[r] = 0.f;
#pragma unroll 4
  for (int c = c0; c < c0 + cn; ++c) {
    float wv = w1[(size_t)c * 512 + j];
#pragma unroll
    for (int r = 0; r < 16; ++r)
      acc[r] += ft[(size_t)(r0 + r) * 2500 + c] * wv;  // uniform -> s_load
  }
#pragma unroll
  for (int r = 0; r < 16; ++r)
    part[(size_t)ch * 131072 + (r0 + r) * 512 + j] = acc[r];
}

__global__ void __launch_bounds__(256) mm1_comb_k(const float* __restrict__ part,
                                                  const float* __restrict__ b1,
                                                  float* __restrict__ t1) {
  int idx = blockIdx.x * 256 + threadIdx.x;
  if (idx >= 131072) return;
  float s = b1[idx & 511];
#pragma unroll
  for (int ch = 0; ch < 16; ++ch) s += part[(size_t)ch * 131072 + idx];
  t1[idx] = s;
}

// ---------------- per-sample tail
__global__ void __launch_bounds__(512) hg_tail_k(const float* __restrict__ G,
                                                 const float* __restrict__ t1,
                                                 const float* __restrict__ w2,
                                                 const float* __restrict__ b2,
                                                 const float* __restrict__ f2,
                                                 float* __restrict__ outv) {
  int b = blockIdx.x;
  __shared__ float zs[32][512];
  __shared__ float t2s[32][32];
  int t = threadIdx.x;
  const float* Gb = G + b * 1024;
  const float* t1b = t1 + b * 16384;
  {
    int j = t;
    float acc[32];
#pragma unroll
    for (int i = 0; i < 32; ++i) acc[i] = 0.f;
    for (int c = 0; c < 32; ++c) {
      float tv = t1b[c * 512 + j];
#pragma unroll
      for (int i = 0; i < 32; ++i) acc[i] += Gb[i * 32 + c] * tv;
    }
#pragma unroll
    for (int i = 0; i < 32; ++i) zs[i][j] = fmaxf(acc[i], 0.f);
  }
  __syncthreads();
#pragma unroll
  for (int e2 = 0; e2 < 2; ++e2) {
    int e = t + e2 * 512;
    int i = e >> 5, jj = e & 31;
    float acc = b2[jj];
    for (int c = 0; c < 512; ++c) acc += zs[i][c] * w2[c * 32 + jj];
    t2s[i][jj] = acc;
  }
  __syncthreads();
  if (t < 32) {
    int j = t;
    float s = 0.f;
    for (int i = 0; i < 32; ++i) {
      float acc = 0.f;
#pragma unroll
      for (int c = 0; c < 32; ++c) acc += Gb[i * 32 + c] * t2s[c][j];
      s += acc;
    }
    outv[b * 32 + j] = s * (1.f / 32.f) + f2[b * 32 + j];
  }
}

// ---------------- head
__global__ void __launch_bounds__(256) head_k(const float* __restrict__ outv,
                                              const float* __restrict__ hw,
                                              const float* __restrict__ hb,
                                              const float* __restrict__ f2,
                                              float* __restrict__ dout) {
  int i = blockIdx.x * 256 + threadIdx.x;
  if (i < 8000) {
    int b = i / 1000, j = i % 1000;
    float acc = hb[j];
#pragma unroll
    for (int c = 0; c < 32; ++c) acc += outv[b * 32 + c] * hw[c * 1000 + j];
    dout[i] = acc;
  }
  if (i < 256) dout[8000 + i] = f2[i];
}

extern "C" void kernel_launch(void* const* d_in, const int* in_sizes, int n_in,
                              void* d_out, int out_size, void* d_ws, size_t ws_size,
                              hipStream_t stream) {
  const float* x     = (const float*)d_in[0];
  const float* xf    = (const float*)d_in[1];
  const float* c1w   = (const float*)d_in[2];
  const float* c1b   = (const float*)d_in[3];
  const float* c2w   = (const float*)d_in[4];
  const float* c2b   = (const float*)d_in[5];
  const float* enc_w = (const float*)d_in[6];
  const float* enc_b = (const float*)d_in[7];
  const float* wq    = (const float*)d_in[8];
  const float* bq    = (const float*)d_in[9];
  const float* wk    = (const float*)d_in[10];
  const float* bk    = (const float*)d_in[11];
  const float* wv    = (const float*)d_in[12];
  const float* bv    = (const float*)d_in[13];
  const float* wo    = (const float*)d_in[14];
  const float* bo    = (const float*)d_in[15];
  const float* dec_w = (const float*)d_in[16];
  const float* dec_b = (const float*)d_in[17];
  const float* w1    = (const float*)d_in[18];
  const float* b1    = (const float*)d_in[19];
  const float* w2    = (const float*)d_in[20];
  const float* b2    = (const float*)d_in[21];
  const float* hw    = (const float*)d_in[22];
  const float* hb    = (const float*)d_in[23];
  float* out = (float*)d_out;

  float* ws = (float*)d_ws;
  // layout (floats):
  float* h1   = ws;                  // [0, 11,520,000)  dead after conv2 partials
  float* ftb  = ws + 11520000;       // 640,000
  float* ftT  = ws + 12160000;       // 640,000
  float* qkv  = ws + 12800000;       // 12,288
  float* ao   = ws + 12812288;       // 4,096
  float* f2   = ws + 12816384;       // 256
  float* outv = ws + 12816640;       // 256
  float* G    = ws + 12816896;       // 8,192  -> 12,825,088
  float* part2= ws + 12825088;       // 5,120,000 -> 17,945,088 (71.8 MB)
  // overlays on ftb region (dead until comb2 writes it):
  float* c1wT = ws + 11520000;       // 4,800
  float* c2wT = ws + 11524800;       // 51,200  -> 11,576,000 < 12,160,000 OK
  // overlays on dead h1 region (used only after conv2 completes):
  float* part = ws;                  // 2,097,152
  float* t1   = ws + 2097152;        // 131,072 -> 2,228,224
  float* gramP= ws + 2228224;        // 204,800 -> 2,433,024

  bool big = ws_size >= (size_t)17945088 * 4;

  wT_k<<<219, 256, 0, stream>>>(c1w, c2w, c1wT, c2wT);
  conv1_k<<<8 * 150, 256, 0, stream>>>(x, c1wT, c1b, h1);
  if (big) {
    conv2p_k<<<8 * 50 * 8, 256, 0, stream>>>(h1, c2wT, part2);
    comb2_k<<<8 * 50, 256, 0, stream>>>(part2, c2b, ftb, ftT);
  } else {
    conv2_fb_k<<<8 * 50, 256, 0, stream>>>(h1, c2w, c2b, ftb, ftT);
  }

  fk_encqkv<<<8, 512, 0, stream>>>(xf, enc_w, enc_b, wq, bq, wk, bk, wv, bv, qkv);
  fk_attn<<<1, 256, 0, stream>>>(qkv, ao);
  fk_odec<<<8, 512, 0, stream>>>(ao, wo, bo, dec_w, dec_b, f2);

  dim3 gg(8, 25);
  hg_gram_k<<<gg, 256, 0, stream>>>(ftT, gramP);
  hg_G2_k<<<8, 256, 0, stream>>>(gramP, G);
  dim3 gm(16, 16);
  hg_mm1_k<<<gm, 512, 0, stream>>>(ftb, w1, part);
  mm1_comb_k<<<512, 256, 0, stream>>>(part, b1, t1);
  hg_tail_k<<<8, 512, 0, stream>>>(G, t1, w2, b2, f2, outv);
  head_k<<<32, 256, 0, stream>>>(outv, hw, hb, f2, out);
}